// Round 5
// baseline (11732.940 us; speedup 1.0000x reference)
//
#include <hip/hip_runtime.h>
#include <stdint.h>

#define DEVFN __device__ __forceinline__
#define SCOPE_AGENT __HIP_MEMORY_SCOPE_AGENT

static constexpr int B_ = 16;
static constexpr int S_ = 1024;
static constexpr int FR = 128;     // FULL_RANGE
static constexpr int MU = 32;      // MOOD_UNITS
static constexpr int H_ = 512;     // UNITS
static constexpr int G4 = 2048;    // 4*H

// packed-weight chunk counts (16B chunks of 8 bf16 weights)
static constexpr int NCH_WHH = 4 * 4 * 16 * 2048;          // 524288
static constexpr int NCH_WI0 = 4 * 4 * 2048;               // 32768
static constexpr int NCH_WIR = 3 * 4 * 16 * 2048;          // 393216
static constexpr int NCH_TOT = NCH_WHH + NCH_WI0 + NCH_WIR;

static constexpr int HPH = 128 * 512;   // h-pairs per phase (max 128 sub-batches)

DEVFN float blo(uint32_t w) { return __uint_as_float(w << 16); }
DEVFN float bhi(uint32_t w) { return __uint_as_float(w & 0xffff0000u); }
DEVFN uint32_t pack_bf16(float a, float b) {
    uint32_t ua = __float_as_uint(a); ua += 0x7fffu + ((ua >> 16) & 1u);
    uint32_t ub = __float_as_uint(b); ub += 0x7fffu + ((ub >> 16) & 1u);
    return (ua >> 16) | (ub & 0xffff0000u);
}
DEVFN float sigm(float x) { return 1.0f / (1.0f + __expf(-x)); }
DEVFN float tanhfast(float x) {
    float e = __expf(2.0f * fabsf(x));
    float r = 1.0f - 2.0f / (e + 1.0f);   // e==inf -> r=1
    return copysignf(r, x);
}
// 1 packed chunk (8 bf16 weights for 8 consecutive k) . 8 floats
DEVFN float dot8a(uint4 w, const float4* __restrict__ p, float s) {
    float4 a = p[0], b = p[1];
    s = fmaf(blo(w.x), a.x, s); s = fmaf(bhi(w.x), a.y, s);
    s = fmaf(blo(w.y), a.z, s); s = fmaf(bhi(w.y), a.w, s);
    s = fmaf(blo(w.z), b.x, s); s = fmaf(bhi(w.z), b.y, s);
    s = fmaf(blo(w.w), b.z, s); s = fmaf(bhi(w.w), b.w, s);
    return s;
}

// ---------------------------------------------------------------------------
// mood: m = moods@W_mood.T + b_mood ; mc[b][row] = m@Wih0[:,128:160].T + bih0 + bhh0
// ---------------------------------------------------------------------------
__global__ __launch_bounds__(256) void mood_kernel(
    const float* __restrict__ moods, const float* __restrict__ W_mood,
    const float* __restrict__ b_mood, const float* __restrict__ W_ih0,
    const float* __restrict__ b_ih0, const float* __restrict__ b_hh0,
    float* __restrict__ mc)
{
    int b = blockIdx.x, tid = threadIdx.x;
    __shared__ float m[MU];
    if (tid < MU) {
        float s = b_mood[tid];
        #pragma unroll
        for (int j = 0; j < 4; j++) s += moods[b * 4 + j] * W_mood[tid * 4 + j];
        m[tid] = s;
    }
    __syncthreads();
    for (int row = tid; row < G4; row += 256) {
        float s = b_ih0[row] + b_hh0[row];
        const float* w = W_ih0 + (size_t)row * (FR + MU) + FR;
        #pragma unroll
        for (int u = 0; u < MU; u++) s += m[u] * w[u];
        mc[(size_t)b * G4 + row] = s;
    }
}

// ---------------------------------------------------------------------------
// Pre-pack weights to bf16 chunks, one thread per 16B chunk.
// pwh layout : [(l*4+kg)*16 + j][row 0..2047]   (k-range kg*128 + j*8 .. +8)
// pwi0       : [kg*4 + j][row]                  (k-range kg*32  + j*8 .. +8)
// pwir       : [(l*4+kg)*16 + j][row]           (l = layer-1)
// ---------------------------------------------------------------------------
__global__ __launch_bounds__(256) void pack_kernel(
    const float* __restrict__ W_hh0, const float* __restrict__ W_hh_r,
    const float* __restrict__ W_ih0, const float* __restrict__ W_ih_r,
    uint4* __restrict__ pwh, uint4* __restrict__ pwi0, uint4* __restrict__ pwir)
{
    int c = blockIdx.x * 256 + threadIdx.x;
    if (c >= NCH_TOT) return;
    const float* src;
    uint4* dst;
    if (c < NCH_WHH) {
        int l = c >> 17, kg = (c >> 15) & 3, j = (c >> 11) & 15, row = c & 2047;
        const float* W = (l == 0) ? W_hh0 : W_hh_r + (size_t)(l - 1) * G4 * H_;
        src = W + (size_t)row * H_ + kg * 128 + j * 8;
        dst = pwh + c;
    } else if (c < NCH_WHH + NCH_WI0) {
        int d = c - NCH_WHH;
        int kg = d >> 13, j = (d >> 11) & 3, row = d & 2047;
        src = W_ih0 + (size_t)row * (FR + MU) + kg * 32 + j * 8;
        dst = pwi0 + d;
    } else {
        int e = c - NCH_WHH - NCH_WI0;
        int l = e >> 17, kg = (e >> 15) & 3, j = (e >> 11) & 15, row = e & 2047;
        src = W_ih_r + (size_t)l * G4 * H_ + (size_t)row * H_ + kg * 128 + j * 8;
        dst = pwir + e;
    }
    uint4 o;
    o.x = pack_bf16(src[0], src[1]);
    o.y = pack_bf16(src[2], src[3]);
    o.z = pack_bf16(src[4], src[5]);
    o.w = pack_bf16(src[6], src[7]);
    *dst = o;
}

// ---------------------------------------------------------------------------
// Persistent dilated-LSTM scan. 16 groups x 16 WGs x 512 threads.
// Weights streamed from L2 (R4, proven). NEW: data-carrying handshake --
// h element = 8B {f32 value, u32 tag} pair stored with ONE 64-bit agent
// atomic; readers poll their own pair until tag==base+t. Replaces counter
// arrive+poll+load (4 serial RTTs) with ~1 visibility RTT. Double-buffered
// by step parity (overwrite gated one full step behind consumption -> no
// deadlock). Tags monotonic across layers -> no stale alias; pairs memset
// per launch -> replay-safe. Prologue publishes h_{-1}=0 with tag=base
// AFTER draining its x-prefetch: uniform step body + closes the t=0
// in-place-x race. All x/h cross-WG traffic agent-scope (no XCD assumption).
// ---------------------------------------------------------------------------
template <int LAYER>
__global__ __launch_bounds__(512, 2) void scan_kernel(
    const float* __restrict__ x_in, float* __restrict__ x_out,
    const uint4* __restrict__ pwi, const uint4* __restrict__ pwh,
    const float* __restrict__ biasA, const float* __restrict__ biasB,
    unsigned long long* __restrict__ hp, unsigned int tagbase)
{
    constexpr int DIL = 1 << LAYER;
    constexpr int SB = DIL;                  // sub-batches per group
    constexpr int T = S_ / DIL;
    constexpr int KIN = (LAYER == 0) ? FR : H_;
    constexpr int KW = KIN / 4;              // k-range per kg for Wih
    constexpr int NJX = KW / 8;              // Wih chunks/thread (4 or 16)
    constexpr int NJH = 16;                  // Whh chunks/thread
    constexpr int XTOT = SB * KIN;           // staged floats per WG per step
    constexpr int XRS = (XTOT + 511) / 512;  // staged floats per thread
    constexpr int KSH = (LAYER == 0) ? 7 : 9;
    constexpr int LOFF = (LAYER == 0) ? 0 : (LAYER - 1);

    const int bid = blockIdx.x;
    const int g = bid & 15, wgi = bid >> 4;
    const int tid = threadIdx.x;
    const int kg = tid >> 7, r = tid & 127;
    const int U0 = wgi * 32;
    const int Rrow = (r >> 5) * H_ + U0 + (r & 31);   // global gate row
    const int sb0 = g * SB;

    __shared__ __align__(16) float lds_x[SB][KIN];
    __shared__ __align__(16) float lds_h[SB][H_];
    __shared__ float lds_p[SB][128 * 5];     // padded [128][5] partials

    const uint4* WI = pwi + ((size_t)(LOFF * 4 + kg) * NJX) * G4 + Rrow;
    const uint4* WH = pwh + ((size_t)(LAYER * 4 + kg) * 16) * G4 + Rrow;

    // ---- per-update-thread bias + cell state ----
    const int b0 = tid >> 5, uu = tid & 31;
    const bool upd = tid < SB * 32;
    float biasv[4] = {0.f, 0.f, 0.f, 0.f};
    float cst = 0.0f;
    if (upd) {
        #pragma unroll
        for (int Gx = 0; Gx < 4; Gx++) {
            int RR = Gx * H_ + U0 + uu;
            if constexpr (LAYER == 0)
                biasv[Gx] = biasA[(size_t)(sb0 + b0) * G4 + RR];   // mc (incl. biases)
            else
                biasv[Gx] = biasA[RR] + biasB[RR];
        }
    }
    const size_t wslot = (size_t)(sb0 + b0) * 512 + U0 + uu;   // pair this thread writes

    // ---- prologue: prefetch token 0 ----
    float xsr[XRS];
    #pragma unroll
    for (int rr = 0; rr < XRS; rr++) {
        int idx = tid + rr * 512;
        if (idx < XTOT) {
            int b = idx >> KSH, off = idx & (KIN - 1);
            int sb = sb0 + b, bg = sb >> LAYER, k = sb & (DIL - 1);
            xsr[rr] = __hip_atomic_load(
                x_in + ((size_t)bg * S_ + k) * KIN + off,
                __ATOMIC_RELAXED, SCOPE_AGENT);
        }
    }
    // drain prologue prefetch, then publish h_{-1}=0 with tag=base (buf[1])
    asm volatile("s_waitcnt vmcnt(0)" ::: "memory");
    __syncthreads();
    if (upd)
        __hip_atomic_store(hp + HPH + wslot,
                           (unsigned long long)tagbase << 32,
                           __ATOMIC_RELAXED, SCOPE_AGENT);

    float acc[SB];
    for (int t = 0; t < T; t++) {
        // ---- staged regs -> LDS ----
        #pragma unroll
        for (int rr = 0; rr < XRS; rr++) {
            int idx = tid + rr * 512;
            if (idx < XTOT) lds_x[idx >> KSH][idx & (KIN - 1)] = xsr[rr];
        }
        __syncthreads();

        // ---- issue token(t+1) prefetch (drained before our tag stores) ----
        if (t + 1 < T) {
            #pragma unroll
            for (int rr = 0; rr < XRS; rr++) {
                int idx = tid + rr * 512;
                if (idx < XTOT) {
                    int b = idx >> KSH, off = idx & (KIN - 1);
                    int sb = sb0 + b, bg = sb >> LAYER, k = sb & (DIL - 1);
                    xsr[rr] = __hip_atomic_load(
                        x_in + ((size_t)bg * S_ + (size_t)(t + 1) * DIL + k) * KIN + off,
                        __ATOMIC_RELAXED, SCOPE_AGENT);
                }
            }
        }

        // ---- issue first h-pair polls (detect overlaps x-matvec) ----
        const unsigned long long* hrd = hp + (size_t)((t + 1) & 1) * HPH;
        unsigned long long pv[SB];
        #pragma unroll
        for (int b = 0; b < SB; b++)
            pv[b] = __hip_atomic_load(hrd + (size_t)(sb0 + b) * 512 + tid,
                                      __ATOMIC_RELAXED, SCOPE_AGENT);

        // ---- x-part: stream Wih chunks, reuse each across SB ----
        #pragma unroll
        for (int b = 0; b < SB; b++) acc[b] = 0.f;
        #pragma unroll 4
        for (int j = 0; j < NJX; j++) {
            uint4 w = WI[(size_t)j * G4];
            #pragma unroll
            for (int b = 0; b < SB; b++)
                acc[b] = dot8a(w, (const float4*)&lds_x[b][kg * KW + j * 8], acc[b]);
        }

        // ---- complete polls; h values -> LDS ----
        {
            const unsigned int want = tagbase + (unsigned int)t;
            #pragma unroll
            for (int b = 0; b < SB; b++) {
                while ((unsigned int)(pv[b] >> 32) != want)
                    pv[b] = __hip_atomic_load(hrd + (size_t)(sb0 + b) * 512 + tid,
                                              __ATOMIC_RELAXED, SCOPE_AGENT);
                lds_h[b][tid] = __uint_as_float((unsigned int)pv[b]);
            }
        }
        __syncthreads();

        // ---- recurrent part (stream Whh; h=0 at t=0 via prologue pairs) ----
        #pragma unroll 4
        for (int j = 0; j < NJH; j++) {
            uint4 w = WH[(size_t)j * G4];
            #pragma unroll
            for (int b = 0; b < SB; b++)
                acc[b] = dot8a(w, (const float4*)&lds_h[b][kg * 128 + j * 8], acc[b]);
        }

        // ---- reduce partials across the 4 k-quadrants ----
        #pragma unroll
        for (int b = 0; b < SB; b++) lds_p[b][r * 5 + kg] = acc[b];
        __syncthreads();

        // ---- gate nonlinearity + cell/hidden update (SB*32 threads) ----
        float hv = 0.f;
        if (upd) {
            float gv[4];
            #pragma unroll
            for (int Gx = 0; Gx < 4; Gx++) {
                int rr = Gx * 32 + uu;
                gv[Gx] = lds_p[b0][rr * 5 + 0] + lds_p[b0][rr * 5 + 1] +
                         lds_p[b0][rr * 5 + 2] + lds_p[b0][rr * 5 + 3] + biasv[Gx];
            }
            float ci = sigm(gv[0]), cf = sigm(gv[1]);
            float cg = tanhfast(gv[2]), co = sigm(gv[3]);
            cst = cf * cst + ci * cg;
            hv = co * tanhfast(cst);
            int sb = sb0 + b0, bg = sb >> LAYER, k = sb & (DIL - 1);
            float res;
            if constexpr (LAYER > 0) res = lds_x[b0][U0 + uu]; else res = 0.f;
            __hip_atomic_store(x_out + ((size_t)bg * S_ + (size_t)t * DIL + k) * H_ + U0 + uu,
                               hv + res, __ATOMIC_RELAXED, SCOPE_AGENT);
        }

        // ---- drain ALL threads' x-prefetch, then publish h_t pairs ----
        asm volatile("s_waitcnt vmcnt(0)" ::: "memory");
        __syncthreads();
        if (upd) {
            unsigned long long pk =
                ((unsigned long long)(tagbase + (unsigned int)t + 1) << 32) |
                (unsigned long long)__float_as_uint(hv);
            __hip_atomic_store(hp + (size_t)(t & 1) * HPH + wslot,
                               pk, __ATOMIC_RELAXED, SCOPE_AGENT);
        }
    }
}

// ---------------------------------------------------------------------------
// out = x @ W_out.T + b_out   ([16384,512] x [512,128])
// ---------------------------------------------------------------------------
__global__ __launch_bounds__(256) void out_gemm(
    const float* __restrict__ x, const float* __restrict__ Wout,
    const float* __restrict__ bout, float* __restrict__ out)
{
    __shared__ __align__(16) float xs[8][H_];
    int tid = threadIdx.x;
    size_t tok0 = (size_t)blockIdx.x * 8;
    const float4* src = (const float4*)(x + tok0 * H_);
    for (int idx = tid; idx < 8 * H_ / 4; idx += 256)
        ((float4*)xs)[idx] = src[idx];
    __syncthreads();

    int col = tid & 127, th = tid >> 7;
    int tb = th * 4;
    float a0 = 0.f, a1 = 0.f, a2 = 0.f, a3 = 0.f;
    const float4* w = (const float4*)(Wout + (size_t)col * H_);
    #pragma unroll 4
    for (int j = 0; j < H_ / 4; j++) {
        float4 wv = w[j];
        float4 x0 = ((const float4*)xs[tb + 0])[j];
        float4 x1 = ((const float4*)xs[tb + 1])[j];
        float4 x2 = ((const float4*)xs[tb + 2])[j];
        float4 x3 = ((const float4*)xs[tb + 3])[j];
        a0 = fmaf(wv.x, x0.x, a0); a0 = fmaf(wv.y, x0.y, a0); a0 = fmaf(wv.z, x0.z, a0); a0 = fmaf(wv.w, x0.w, a0);
        a1 = fmaf(wv.x, x1.x, a1); a1 = fmaf(wv.y, x1.y, a1); a1 = fmaf(wv.z, x1.z, a1); a1 = fmaf(wv.w, x1.w, a1);
        a2 = fmaf(wv.x, x2.x, a2); a2 = fmaf(wv.y, x2.y, a2); a2 = fmaf(wv.z, x2.z, a2); a2 = fmaf(wv.w, x2.w, a2);
        a3 = fmaf(wv.x, x3.x, a3); a3 = fmaf(wv.y, x3.y, a3); a3 = fmaf(wv.z, x3.z, a3); a3 = fmaf(wv.w, x3.w, a3);
    }
    float bo = bout[col];
    out[(tok0 + tb + 0) * FR + col] = a0 + bo;
    out[(tok0 + tb + 1) * FR + col] = a1 + bo;
    out[(tok0 + tb + 2) * FR + col] = a2 + bo;
    out[(tok0 + tb + 3) * FR + col] = a3 + bo;
}

// ---------------------------------------------------------------------------
extern "C" void kernel_launch(void* const* d_in, const int* in_sizes, int n_in,
                              void* d_out, int out_size, void* d_ws, size_t ws_size,
                              hipStream_t stream)
{
    const float* inputs = (const float*)d_in[0];
    const float* moods  = (const float*)d_in[1];
    const float* W_mood = (const float*)d_in[2];
    const float* b_mood = (const float*)d_in[3];
    const float* W_ih0  = (const float*)d_in[4];
    const float* W_hh0  = (const float*)d_in[5];
    const float* b_ih0  = (const float*)d_in[6];
    const float* b_hh0  = (const float*)d_in[7];
    const float* W_ih_r = (const float*)d_in[8];
    const float* W_hh_r = (const float*)d_in[9];
    const float* b_ih_r = (const float*)d_in[10];
    const float* b_hh_r = (const float*)d_in[11];
    const float* W_out  = (const float*)d_in[12];
    const float* b_out  = (const float*)d_in[13];

    float* ws = (float*)d_ws;
    float* mc = ws;                                    // 32768 floats
    float* xA = ws + 32768;                            // 8388608 floats (in-place x)
    unsigned long long* hp = (unsigned long long*)(xA + 8388608);  // 2*HPH pairs = 1MB
    uint4* pwh  = (uint4*)(hp + 2 * HPH);              // 524288 uint4
    uint4* pwi0 = pwh + NCH_WHH;                       // 32768 uint4
    uint4* pwir = pwi0 + NCH_WI0;                      // 393216 uint4
    // total ~50 MB

    hipMemsetAsync(hp, 0, 2 * HPH * sizeof(unsigned long long), stream);
    mood_kernel<<<16, 256, 0, stream>>>(moods, W_mood, b_mood, W_ih0, b_ih0, b_hh0, mc);
    pack_kernel<<<(NCH_TOT + 255) / 256, 256, 0, stream>>>(
        W_hh0, W_hh_r, W_ih0, W_ih_r, pwh, pwi0, pwir);

    // tag bases: layer L uses tags [base, base+T]; strictly increasing across
    // layers so stale tags never alias. L0:1..1025, L1:1026..1538,
    // L2:1539..1795, L3:1796..1924.
    scan_kernel<0><<<256, 512, 0, stream>>>(inputs, xA, pwi0, pwh, mc, nullptr, hp, 1u);
    scan_kernel<1><<<256, 512, 0, stream>>>(xA, xA, pwir, pwh,
                                            b_ih_r, b_hh_r, hp, 1026u);
    scan_kernel<2><<<256, 512, 0, stream>>>(xA, xA, pwir, pwh,
                                            b_ih_r + G4, b_hh_r + G4, hp, 1539u);
    scan_kernel<3><<<256, 512, 0, stream>>>(xA, xA, pwir, pwh,
                                            b_ih_r + 2 * G4, b_hh_r + 2 * G4, hp, 1796u);

    out_gemm<<<2048, 256, 0, stream>>>(xA, W_out, b_out, (float*)d_out);
}

// Round 6
// 8899.236 us; speedup vs baseline: 1.3184x; 1.3184x over previous
//
#include <hip/hip_runtime.h>
#include <stdint.h>

#define DEVFN __device__ __forceinline__
#define SCOPE_AGENT __HIP_MEMORY_SCOPE_AGENT

static constexpr int B_ = 16;
static constexpr int S_ = 1024;
static constexpr int FR = 128;     // FULL_RANGE
static constexpr int MU = 32;      // MOOD_UNITS
static constexpr int H_ = 512;     // UNITS
static constexpr int G4 = 2048;    // 4*H

// packed-weight chunk counts (16B chunks of 8 bf16 weights)
static constexpr int NCH_WHH = 4 * 4 * 16 * 2048;          // 524288
static constexpr int NCH_WI0 = 4 * 4 * 2048;               // 32768
static constexpr int NCH_WIR = 3 * 4 * 16 * 2048;          // 393216
static constexpr int NCH_TOT = NCH_WHH + NCH_WI0 + NCH_WIR;

static constexpr int HPH = 128 * 512;   // h-pairs per phase (max 128 sub-batches)

DEVFN float blo(uint32_t w) { return __uint_as_float(w << 16); }
DEVFN float bhi(uint32_t w) { return __uint_as_float(w & 0xffff0000u); }
DEVFN uint32_t pack_bf16(float a, float b) {
    uint32_t ua = __float_as_uint(a); ua += 0x7fffu + ((ua >> 16) & 1u);
    uint32_t ub = __float_as_uint(b); ub += 0x7fffu + ((ub >> 16) & 1u);
    return (ua >> 16) | (ub & 0xffff0000u);
}
DEVFN float sigm(float x) { return 1.0f / (1.0f + __expf(-x)); }
DEVFN float tanhfast(float x) {
    float e = __expf(2.0f * fabsf(x));
    float r = 1.0f - 2.0f / (e + 1.0f);   // e==inf -> r=1
    return copysignf(r, x);
}
// 1 packed chunk (8 bf16 weights for 8 consecutive k) . 8 floats
DEVFN float dot8a(uint4 w, const float4* __restrict__ p, float s) {
    float4 a = p[0], b = p[1];
    s = fmaf(blo(w.x), a.x, s); s = fmaf(bhi(w.x), a.y, s);
    s = fmaf(blo(w.y), a.z, s); s = fmaf(bhi(w.y), a.w, s);
    s = fmaf(blo(w.z), b.x, s); s = fmaf(bhi(w.z), b.y, s);
    s = fmaf(blo(w.w), b.z, s); s = fmaf(bhi(w.w), b.w, s);
    return s;
}

// ---------------------------------------------------------------------------
// mood: m = moods@W_mood.T + b_mood ; mc[b][row] = m@Wih0[:,128:160].T + bih0 + bhh0
// ---------------------------------------------------------------------------
__global__ __launch_bounds__(256) void mood_kernel(
    const float* __restrict__ moods, const float* __restrict__ W_mood,
    const float* __restrict__ b_mood, const float* __restrict__ W_ih0,
    const float* __restrict__ b_ih0, const float* __restrict__ b_hh0,
    float* __restrict__ mc)
{
    int b = blockIdx.x, tid = threadIdx.x;
    __shared__ float m[MU];
    if (tid < MU) {
        float s = b_mood[tid];
        #pragma unroll
        for (int j = 0; j < 4; j++) s += moods[b * 4 + j] * W_mood[tid * 4 + j];
        m[tid] = s;
    }
    __syncthreads();
    for (int row = tid; row < G4; row += 256) {
        float s = b_ih0[row] + b_hh0[row];
        const float* w = W_ih0 + (size_t)row * (FR + MU) + FR;
        #pragma unroll
        for (int u = 0; u < MU; u++) s += m[u] * w[u];
        mc[(size_t)b * G4 + row] = s;
    }
}

// ---------------------------------------------------------------------------
// Pre-pack weights to bf16 chunks, one thread per 16B chunk.
// pwh layout : [(l*4+kg)*16 + j][row 0..2047]   (k-range kg*128 + j*8 .. +8)
// pwi0       : [kg*4 + j][row]                  (k-range kg*32  + j*8 .. +8)
// pwir       : [(l*4+kg)*16 + j][row]           (l = layer-1)
// ---------------------------------------------------------------------------
__global__ __launch_bounds__(256) void pack_kernel(
    const float* __restrict__ W_hh0, const float* __restrict__ W_hh_r,
    const float* __restrict__ W_ih0, const float* __restrict__ W_ih_r,
    uint4* __restrict__ pwh, uint4* __restrict__ pwi0, uint4* __restrict__ pwir)
{
    int c = blockIdx.x * 256 + threadIdx.x;
    if (c >= NCH_TOT) return;
    const float* src;
    uint4* dst;
    if (c < NCH_WHH) {
        int l = c >> 17, kg = (c >> 15) & 3, j = (c >> 11) & 15, row = c & 2047;
        const float* W = (l == 0) ? W_hh0 : W_hh_r + (size_t)(l - 1) * G4 * H_;
        src = W + (size_t)row * H_ + kg * 128 + j * 8;
        dst = pwh + c;
    } else if (c < NCH_WHH + NCH_WI0) {
        int d = c - NCH_WHH;
        int kg = d >> 13, j = (d >> 11) & 3, row = d & 2047;
        src = W_ih0 + (size_t)row * (FR + MU) + kg * 32 + j * 8;
        dst = pwi0 + d;
    } else {
        int e = c - NCH_WHH - NCH_WI0;
        int l = e >> 17, kg = (e >> 15) & 3, j = (e >> 11) & 15, row = e & 2047;
        src = W_ih_r + (size_t)l * G4 * H_ + (size_t)row * H_ + kg * 128 + j * 8;
        dst = pwir + e;
    }
    uint4 o;
    o.x = pack_bf16(src[0], src[1]);
    o.y = pack_bf16(src[2], src[3]);
    o.z = pack_bf16(src[4], src[5]);
    o.w = pack_bf16(src[6], src[7]);
    *dst = o;
}

// chunk J of register-resident Whh applied to all SB sub-batches
#define HCH(WREG, J) { \
    _Pragma("unroll") \
    for (int b = 0; b < SB; b++) \
        acc[b] = dot8a(WREG, (const float4*)&lds_h[b][kg * 128 + (J) * 8], acc[b]); }

// ---------------------------------------------------------------------------
// Persistent dilated-LSTM scan. 16 groups x 16 WGs x 512 threads.
// R5 finding: per-step cost was dominated by the WEIGHT STREAM -- two
// free-running groups per XCD each pull 4MB/step through the 4MB L2 ->
// thrash to L3 (~4us/step), not by the handshake.
// NEW: Whh (16 chunks = 64 VGPR) lives in 16 NAMED uint4 registers, loaded
// once; amdgpu_waves_per_eu(2,2) pins the allocator at 2 waves/EU (1 WG/CU,
// our co-residency requirement) so the 256-VGPR budget is actually used
// (R2/R3 failure: allocator targeted 4 waves/EU -> 128 VGPR -> spill).
// Halves per-step L2/L3 traffic; post-poll h-matvec is pure VALU.
// Data-carrying handshake (R5): h = {f32,tag} 8B pair, 1 visibility RTT.
// ---------------------------------------------------------------------------
template <int LAYER>
__global__ __attribute__((amdgpu_waves_per_eu(2, 2))) __launch_bounds__(512)
void scan_kernel(
    const float* __restrict__ x_in, float* __restrict__ x_out,
    const uint4* __restrict__ pwi, const uint4* __restrict__ pwh,
    const float* __restrict__ biasA, const float* __restrict__ biasB,
    unsigned long long* __restrict__ hp, unsigned int tagbase)
{
    constexpr int DIL = 1 << LAYER;
    constexpr int SB = DIL;                  // sub-batches per group
    constexpr int T = S_ / DIL;
    constexpr int KIN = (LAYER == 0) ? FR : H_;
    constexpr int KW = KIN / 4;              // k-range per kg for Wih
    constexpr int NJX = KW / 8;              // Wih chunks/thread (4 or 16)
    constexpr int XTOT = SB * KIN;           // staged floats per WG per step
    constexpr int XRS = (XTOT + 511) / 512;  // staged floats per thread
    constexpr int KSH = (LAYER == 0) ? 7 : 9;
    constexpr int LOFF = (LAYER == 0) ? 0 : (LAYER - 1);

    const int bid = blockIdx.x;
    const int g = bid & 15, wgi = bid >> 4;
    const int tid = threadIdx.x;
    const int kg = tid >> 7, r = tid & 127;
    const int U0 = wgi * 32;
    const int Rrow = (r >> 5) * H_ + U0 + (r & 31);   // global gate row
    const int sb0 = g * SB;

    __shared__ __align__(16) float lds_x[SB][KIN];
    __shared__ __align__(16) float lds_h[SB][H_];
    __shared__ float lds_p[SB][128 * 5];     // padded [128][5] partials

    const uint4* WI = pwi + ((size_t)(LOFF * 4 + kg) * NJX) * G4 + Rrow;
    const uint4* WH = pwh + ((size_t)(LAYER * 4 + kg) * 16) * G4 + Rrow;

    // ---- Whh chunks -> 16 named registers (64 VGPR), loaded ONCE ----
    uint4 wh0  = WH[(size_t) 0 * G4], wh1  = WH[(size_t) 1 * G4];
    uint4 wh2  = WH[(size_t) 2 * G4], wh3  = WH[(size_t) 3 * G4];
    uint4 wh4  = WH[(size_t) 4 * G4], wh5  = WH[(size_t) 5 * G4];
    uint4 wh6  = WH[(size_t) 6 * G4], wh7  = WH[(size_t) 7 * G4];
    uint4 wh8  = WH[(size_t) 8 * G4], wh9  = WH[(size_t) 9 * G4];
    uint4 wh10 = WH[(size_t)10 * G4], wh11 = WH[(size_t)11 * G4];
    uint4 wh12 = WH[(size_t)12 * G4], wh13 = WH[(size_t)13 * G4];
    uint4 wh14 = WH[(size_t)14 * G4], wh15 = WH[(size_t)15 * G4];

    // ---- per-update-thread bias + cell state ----
    const int b0 = tid >> 5, uu = tid & 31;
    const bool upd = tid < SB * 32;
    float biasv[4] = {0.f, 0.f, 0.f, 0.f};
    float cst = 0.0f;
    if (upd) {
        #pragma unroll
        for (int Gx = 0; Gx < 4; Gx++) {
            int RR = Gx * H_ + U0 + uu;
            if constexpr (LAYER == 0)
                biasv[Gx] = biasA[(size_t)(sb0 + b0) * G4 + RR];   // mc (incl. biases)
            else
                biasv[Gx] = biasA[RR] + biasB[RR];
        }
    }
    const size_t wslot = (size_t)(sb0 + b0) * 512 + U0 + uu;   // pair this thread writes

    // ---- prologue: prefetch token 0 ----
    float xsr[XRS];
    #pragma unroll
    for (int rr = 0; rr < XRS; rr++) {
        int idx = tid + rr * 512;
        if (idx < XTOT) {
            int b = idx >> KSH, off = idx & (KIN - 1);
            int sb = sb0 + b, bg = sb >> LAYER, k = sb & (DIL - 1);
            xsr[rr] = __hip_atomic_load(
                x_in + ((size_t)bg * S_ + k) * KIN + off,
                __ATOMIC_RELAXED, SCOPE_AGENT);
        }
    }
    // drain prologue prefetch, then publish h_{-1}=0 with tag=base (buf[1])
    asm volatile("s_waitcnt vmcnt(0)" ::: "memory");
    __syncthreads();
    if (upd)
        __hip_atomic_store(hp + HPH + wslot,
                           (unsigned long long)tagbase << 32,
                           __ATOMIC_RELAXED, SCOPE_AGENT);

    float acc[SB];
    for (int t = 0; t < T; t++) {
        // ---- staged regs -> LDS ----
        #pragma unroll
        for (int rr = 0; rr < XRS; rr++) {
            int idx = tid + rr * 512;
            if (idx < XTOT) lds_x[idx >> KSH][idx & (KIN - 1)] = xsr[rr];
        }
        __syncthreads();

        // ---- issue token(t+1) prefetch (drained before our tag stores) ----
        if (t + 1 < T) {
            #pragma unroll
            for (int rr = 0; rr < XRS; rr++) {
                int idx = tid + rr * 512;
                if (idx < XTOT) {
                    int b = idx >> KSH, off = idx & (KIN - 1);
                    int sb = sb0 + b, bg = sb >> LAYER, k = sb & (DIL - 1);
                    xsr[rr] = __hip_atomic_load(
                        x_in + ((size_t)bg * S_ + (size_t)(t + 1) * DIL + k) * KIN + off,
                        __ATOMIC_RELAXED, SCOPE_AGENT);
                }
            }
        }

        // ---- issue first h-pair polls (detect overlaps x-matvec) ----
        const unsigned long long* hrd = hp + (size_t)((t + 1) & 1) * HPH;
        unsigned long long pv[SB];
        #pragma unroll
        for (int b = 0; b < SB; b++)
            pv[b] = __hip_atomic_load(hrd + (size_t)(sb0 + b) * 512 + tid,
                                      __ATOMIC_RELAXED, SCOPE_AGENT);

        // ---- x-part: stream Wih chunks (off critical path), reuse per SB ----
        #pragma unroll
        for (int b = 0; b < SB; b++) acc[b] = 0.f;
        #pragma unroll 4
        for (int j = 0; j < NJX; j++) {
            uint4 w = WI[(size_t)j * G4];
            #pragma unroll
            for (int b = 0; b < SB; b++)
                acc[b] = dot8a(w, (const float4*)&lds_x[b][kg * KW + j * 8], acc[b]);
        }

        // ---- complete polls; h values -> LDS ----
        {
            const unsigned int want = tagbase + (unsigned int)t;
            #pragma unroll
            for (int b = 0; b < SB; b++) {
                while ((unsigned int)(pv[b] >> 32) != want)
                    pv[b] = __hip_atomic_load(hrd + (size_t)(sb0 + b) * 512 + tid,
                                              __ATOMIC_RELAXED, SCOPE_AGENT);
                lds_h[b][tid] = __uint_as_float((unsigned int)pv[b]);
            }
        }
        __syncthreads();

        // ---- recurrent part: register-resident Whh, pure VALU ----
        HCH(wh0,  0)  HCH(wh1,  1)  HCH(wh2,  2)  HCH(wh3,  3)
        HCH(wh4,  4)  HCH(wh5,  5)  HCH(wh6,  6)  HCH(wh7,  7)
        HCH(wh8,  8)  HCH(wh9,  9)  HCH(wh10, 10) HCH(wh11, 11)
        HCH(wh12, 12) HCH(wh13, 13) HCH(wh14, 14) HCH(wh15, 15)

        // ---- reduce partials across the 4 k-quadrants ----
        #pragma unroll
        for (int b = 0; b < SB; b++) lds_p[b][r * 5 + kg] = acc[b];
        __syncthreads();

        // ---- gate nonlinearity + cell/hidden update (SB*32 threads) ----
        float hv = 0.f;
        if (upd) {
            float gv[4];
            #pragma unroll
            for (int Gx = 0; Gx < 4; Gx++) {
                int rr = Gx * 32 + uu;
                gv[Gx] = lds_p[b0][rr * 5 + 0] + lds_p[b0][rr * 5 + 1] +
                         lds_p[b0][rr * 5 + 2] + lds_p[b0][rr * 5 + 3] + biasv[Gx];
            }
            float ci = sigm(gv[0]), cf = sigm(gv[1]);
            float cg = tanhfast(gv[2]), co = sigm(gv[3]);
            cst = cf * cst + ci * cg;
            hv = co * tanhfast(cst);
            int sb = sb0 + b0, bg = sb >> LAYER, k = sb & (DIL - 1);
            float res;
            if constexpr (LAYER > 0) res = lds_x[b0][U0 + uu]; else res = 0.f;
            __hip_atomic_store(x_out + ((size_t)bg * S_ + (size_t)t * DIL + k) * H_ + U0 + uu,
                               hv + res, __ATOMIC_RELAXED, SCOPE_AGENT);
        }

        // ---- drain ALL threads' x-prefetch, then publish h_t pairs ----
        asm volatile("s_waitcnt vmcnt(0)" ::: "memory");
        __syncthreads();
        if (upd) {
            unsigned long long pk =
                ((unsigned long long)(tagbase + (unsigned int)t + 1) << 32) |
                (unsigned long long)__float_as_uint(hv);
            __hip_atomic_store(hp + (size_t)(t & 1) * HPH + wslot,
                               pk, __ATOMIC_RELAXED, SCOPE_AGENT);
        }
    }
}

// ---------------------------------------------------------------------------
// out = x @ W_out.T + b_out   ([16384,512] x [512,128])
// ---------------------------------------------------------------------------
__global__ __launch_bounds__(256) void out_gemm(
    const float* __restrict__ x, const float* __restrict__ Wout,
    const float* __restrict__ bout, float* __restrict__ out)
{
    __shared__ __align__(16) float xs[8][H_];
    int tid = threadIdx.x;
    size_t tok0 = (size_t)blockIdx.x * 8;
    const float4* src = (const float4*)(x + tok0 * H_);
    for (int idx = tid; idx < 8 * H_ / 4; idx += 256)
        ((float4*)xs)[idx] = src[idx];
    __syncthreads();

    int col = tid & 127, th = tid >> 7;
    int tb = th * 4;
    float a0 = 0.f, a1 = 0.f, a2 = 0.f, a3 = 0.f;
    const float4* w = (const float4*)(Wout + (size_t)col * H_);
    #pragma unroll 4
    for (int j = 0; j < H_ / 4; j++) {
        float4 wv = w[j];
        float4 x0 = ((const float4*)xs[tb + 0])[j];
        float4 x1 = ((const float4*)xs[tb + 1])[j];
        float4 x2 = ((const float4*)xs[tb + 2])[j];
        float4 x3 = ((const float4*)xs[tb + 3])[j];
        a0 = fmaf(wv.x, x0.x, a0); a0 = fmaf(wv.y, x0.y, a0); a0 = fmaf(wv.z, x0.z, a0); a0 = fmaf(wv.w, x0.w, a0);
        a1 = fmaf(wv.x, x1.x, a1); a1 = fmaf(wv.y, x1.y, a1); a1 = fmaf(wv.z, x1.z, a1); a1 = fmaf(wv.w, x1.w, a1);
        a2 = fmaf(wv.x, x2.x, a2); a2 = fmaf(wv.y, x2.y, a2); a2 = fmaf(wv.z, x2.z, a2); a2 = fmaf(wv.w, x2.w, a2);
        a3 = fmaf(wv.x, x3.x, a3); a3 = fmaf(wv.y, x3.y, a3); a3 = fmaf(wv.z, x3.z, a3); a3 = fmaf(wv.w, x3.w, a3);
    }
    float bo = bout[col];
    out[(tok0 + tb + 0) * FR + col] = a0 + bo;
    out[(tok0 + tb + 1) * FR + col] = a1 + bo;
    out[(tok0 + tb + 2) * FR + col] = a2 + bo;
    out[(tok0 + tb + 3) * FR + col] = a3 + bo;
}

// ---------------------------------------------------------------------------
extern "C" void kernel_launch(void* const* d_in, const int* in_sizes, int n_in,
                              void* d_out, int out_size, void* d_ws, size_t ws_size,
                              hipStream_t stream)
{
    const float* inputs = (const float*)d_in[0];
    const float* moods  = (const float*)d_in[1];
    const float* W_mood = (const float*)d_in[2];
    const float* b_mood = (const float*)d_in[3];
    const float* W_ih0  = (const float*)d_in[4];
    const float* W_hh0  = (const float*)d_in[5];
    const float* b_ih0  = (const float*)d_in[6];
    const float* b_hh0  = (const float*)d_in[7];
    const float* W_ih_r = (const float*)d_in[8];
    const float* W_hh_r = (const float*)d_in[9];
    const float* b_ih_r = (const float*)d_in[10];
    const float* b_hh_r = (const float*)d_in[11];
    const float* W_out  = (const float*)d_in[12];
    const float* b_out  = (const float*)d_in[13];

    float* ws = (float*)d_ws;
    float* mc = ws;                                    // 32768 floats
    float* xA = ws + 32768;                            // 8388608 floats (in-place x)
    unsigned long long* hp = (unsigned long long*)(xA + 8388608);  // 2*HPH pairs = 1MB
    uint4* pwh  = (uint4*)(hp + 2 * HPH);              // 524288 uint4
    uint4* pwi0 = pwh + NCH_WHH;                       // 32768 uint4
    uint4* pwir = pwi0 + NCH_WI0;                      // 393216 uint4
    // total ~50 MB

    hipMemsetAsync(hp, 0, 2 * HPH * sizeof(unsigned long long), stream);
    mood_kernel<<<16, 256, 0, stream>>>(moods, W_mood, b_mood, W_ih0, b_ih0, b_hh0, mc);
    pack_kernel<<<(NCH_TOT + 255) / 256, 256, 0, stream>>>(
        W_hh0, W_hh_r, W_ih0, W_ih_r, pwh, pwi0, pwir);

    // tag bases: layer L uses tags [base, base+T]; strictly increasing across
    // layers so stale tags never alias.
    scan_kernel<0><<<256, 512, 0, stream>>>(inputs, xA, pwi0, pwh, mc, nullptr, hp, 1u);
    scan_kernel<1><<<256, 512, 0, stream>>>(xA, xA, pwir, pwh,
                                            b_ih_r, b_hh_r, hp, 1026u);
    scan_kernel<2><<<256, 512, 0, stream>>>(xA, xA, pwir, pwh,
                                            b_ih_r + G4, b_hh_r + G4, hp, 1539u);
    scan_kernel<3><<<256, 512, 0, stream>>>(xA, xA, pwir, pwh,
                                            b_ih_r + 2 * G4, b_hh_r + 2 * G4, hp, 1796u);

    out_gemm<<<2048, 256, 0, stream>>>(xA, W_out, b_out, (float*)d_out);
}

// Round 7
// 8789.764 us; speedup vs baseline: 1.3348x; 1.0125x over previous
//
#include <hip/hip_runtime.h>
#include <stdint.h>

#define DEVFN __device__ __forceinline__
#define SCOPE_AGENT __HIP_MEMORY_SCOPE_AGENT

static constexpr int B_ = 16;
static constexpr int S_ = 1024;
static constexpr int FR = 128;     // FULL_RANGE
static constexpr int MU = 32;      // MOOD_UNITS
static constexpr int H_ = 512;     // UNITS
static constexpr int G4 = 2048;    // 4*H

// packed-weight chunk counts (16B chunks of 8 f16 weights)
static constexpr int NCH_WHH = 4 * 64 * 2048;              // 524288
static constexpr int NCH_WI0 = 16 * 2048;                  // 32768
static constexpr int NCH_WIR = 3 * 64 * 2048;              // 393216
static constexpr int NCH_TOT = NCH_WHH + NCH_WI0 + NCH_WIR;

static constexpr int HPH = 128 * 512;   // h-pairs per phase (max 128 sub-batches)

typedef _Float16 h2_t __attribute__((ext_vector_type(2)));

DEVFN uint16_t f2h(float x) { union { _Float16 f; uint16_t u; } c; c.f = (_Float16)x; return c.u; }
DEVFN uint32_t pack_f16(float a, float b) { return (uint32_t)f2h(a) | ((uint32_t)f2h(b) << 16); }

DEVFN float fd2(uint32_t a, uint32_t b, float c) {
#if __has_builtin(__builtin_amdgcn_fdot2)
    return __builtin_amdgcn_fdot2(__builtin_bit_cast(h2_t, a),
                                  __builtin_bit_cast(h2_t, b), c, false);
#else
    asm("v_dot2_f32_f16 %0, %1, %2, %0" : "+v"(c) : "v"(a), "v"(b));
    return c;
#endif
}
// 8 f16 weights . 8 f16 inputs (both as uint4), f32 accumulate
DEVFN float dot8f(uint4 w, uint4 x, float s) {
    s = fd2(w.x, x.x, s); s = fd2(w.y, x.y, s);
    s = fd2(w.z, x.z, s); s = fd2(w.w, x.w, s);
    return s;
}
DEVFN float sigm(float x) { return 1.0f / (1.0f + __expf(-x)); }
DEVFN float tanhfast(float x) {
    float e = __expf(2.0f * fabsf(x));
    float r = 1.0f - 2.0f / (e + 1.0f);   // e==inf -> r=1
    return copysignf(r, x);
}

// ---------------------------------------------------------------------------
// mood: m = moods@W_mood.T + b_mood ; mc[b][row] = m@Wih0[:,128:160].T + bih0 + bhh0
// ---------------------------------------------------------------------------
__global__ __launch_bounds__(256) void mood_kernel(
    const float* __restrict__ moods, const float* __restrict__ W_mood,
    const float* __restrict__ b_mood, const float* __restrict__ W_ih0,
    const float* __restrict__ b_ih0, const float* __restrict__ b_hh0,
    float* __restrict__ mc)
{
    int b = blockIdx.x, tid = threadIdx.x;
    __shared__ float m[MU];
    if (tid < MU) {
        float s = b_mood[tid];
        #pragma unroll
        for (int j = 0; j < 4; j++) s += moods[b * 4 + j] * W_mood[tid * 4 + j];
        m[tid] = s;
    }
    __syncthreads();
    for (int row = tid; row < G4; row += 256) {
        float s = b_ih0[row] + b_hh0[row];
        const float* w = W_ih0 + (size_t)row * (FR + MU) + FR;
        #pragma unroll
        for (int u = 0; u < MU; u++) s += m[u] * w[u];
        mc[(size_t)b * G4 + row] = s;
    }
}

// ---------------------------------------------------------------------------
// Pre-pack weights to f16 chunks (16B = 8 weights), one thread per chunk.
// pwh  : [(l*64 + c)][row 0..2047], c = k/8 in 0..63
// pwi0 : [c][row],                  c = k/8 in 0..15
// pwir : [(l*64 + c)][row]          (l = layer-1)
// ---------------------------------------------------------------------------
__global__ __launch_bounds__(256) void pack_kernel(
    const float* __restrict__ W_hh0, const float* __restrict__ W_hh_r,
    const float* __restrict__ W_ih0, const float* __restrict__ W_ih_r,
    uint4* __restrict__ pwh, uint4* __restrict__ pwi0, uint4* __restrict__ pwir)
{
    int c = blockIdx.x * 256 + threadIdx.x;
    if (c >= NCH_TOT) return;
    const float* src;
    uint4* dst;
    if (c < NCH_WHH) {
        int l = c >> 17, ck = (c >> 11) & 63, row = c & 2047;
        const float* W = (l == 0) ? W_hh0 : W_hh_r + (size_t)(l - 1) * G4 * H_;
        src = W + (size_t)row * H_ + ck * 8;
        dst = pwh + c;
    } else if (c < NCH_WHH + NCH_WI0) {
        int d = c - NCH_WHH;
        int ck = d >> 11, row = d & 2047;
        src = W_ih0 + (size_t)row * (FR + MU) + ck * 8;
        dst = pwi0 + d;
    } else {
        int e = c - NCH_WHH - NCH_WI0;
        int l = e >> 17, ck = (e >> 11) & 63, row = e & 2047;
        src = W_ih_r + (size_t)l * G4 * H_ + (size_t)row * H_ + ck * 8;
        dst = pwir + e;
    }
    uint4 o;
    o.x = pack_f16(src[0], src[1]);
    o.y = pack_f16(src[2], src[3]);
    o.z = pack_f16(src[4], src[5]);
    o.w = pack_f16(src[6], src[7]);
    *dst = o;
}

// register-resident Whh chunk J applied to all SB sub-batches (2 rows/thread)
#define HSTEP(J) { \
    _Pragma("unroll") \
    for (int b = 0; b < SB; b++) { \
        uint4 hv = *(const uint4*)&lds_h[b][kg * 64 + (J) * 8]; \
        accA[b] = dot8f(h0c##J, hv, accA[b]); \
        accB[b] = dot8f(h1c##J, hv, accB[b]); \
    } }

// ---------------------------------------------------------------------------
// Persistent dilated-LSTM scan. 16 groups x 16 WGs x 512 threads.
// R6 finding: dominant per-step cost was VALU ISSUE, 2x-inflated by bf16
// unpack (2 shifts per 2 FMAs) + 2 ds_reads per chunk. NEW: f16 operands on
// BOTH sides -> v_dot2_f32_f16 (1 VALU per 2 MACs), LDS tiles packed f16
// (1 ds_read_b128 per chunk), 2 gate-rows per thread (chunk reused 2x).
// Whh register-resident (R6): 16 named uint4 = 64 VGPR. Protocol: 3 barriers
// per step (drain merged), x_out store after publish, residual via early
// per-thread global load. Data-carrying handshake {f32,tag} 8B pairs (R5).
// ---------------------------------------------------------------------------
template <int LAYER>
__global__ __attribute__((amdgpu_waves_per_eu(2, 2))) __launch_bounds__(512)
void scan_kernel(
    const float* __restrict__ x_in, float* __restrict__ x_out,
    const uint4* __restrict__ pwi, const uint4* __restrict__ pwh,
    const float* __restrict__ biasA, const float* __restrict__ biasB,
    unsigned long long* __restrict__ hp, unsigned int tagbase)
{
    constexpr int DIL = 1 << LAYER;
    constexpr int SB = DIL;                  // sub-batches per group
    constexpr int T = S_ / DIL;
    constexpr int KIN = (LAYER == 0) ? FR : H_;
    constexpr int NJX = KIN / 64;            // x chunks per row per thread (2 or 8)
    constexpr int XTOT = SB * KIN;           // staged floats per WG per step
    constexpr int XRS = (XTOT + 511) / 512;
    constexpr int KSH = (LAYER == 0) ? 7 : 9;
    constexpr int LOFF = (LAYER == 0) ? 0 : (LAYER - 1);

    const int bid = blockIdx.x;
    const int g = bid & 15, wgi = bid >> 4;
    const int tid = threadIdx.x;
    const int kg = tid >> 6;                 // 0..7 : k-segment (64 wide)
    const int r6 = tid & 63;
    const int gp = r6 >> 5;                  // 0..1 : gate pair
    const int um = r6 & 31;                  // unit within WG slice
    const int U0 = wgi * 32;
    const int row0 = (2 * gp) * H_ + U0 + um;        // global gate row (even gate)
    const int row1 = row0 + H_;                      // odd gate
    const int rl0 = (2 * gp) * 32 + um, rl1 = rl0 + 32;  // row-local 0..127
    const int sb0 = g * SB;

    __shared__ __align__(16) uint16_t lds_x[SB][KIN];   // packed f16
    __shared__ __align__(16) uint16_t lds_h[SB][H_];    // packed f16
    __shared__ float lds_p[SB][8][132];                 // partials [sb][kg][row]

    // ---- Whh chunks -> 16 named registers (64 VGPR), loaded ONCE ----
    const uint4* WH = pwh + ((size_t)(LAYER * 64 + kg * 8)) * G4;
    uint4 h0c0 = WH[(size_t)0 * G4 + row0], h1c0 = WH[(size_t)0 * G4 + row1];
    uint4 h0c1 = WH[(size_t)1 * G4 + row0], h1c1 = WH[(size_t)1 * G4 + row1];
    uint4 h0c2 = WH[(size_t)2 * G4 + row0], h1c2 = WH[(size_t)2 * G4 + row1];
    uint4 h0c3 = WH[(size_t)3 * G4 + row0], h1c3 = WH[(size_t)3 * G4 + row1];
    uint4 h0c4 = WH[(size_t)4 * G4 + row0], h1c4 = WH[(size_t)4 * G4 + row1];
    uint4 h0c5 = WH[(size_t)5 * G4 + row0], h1c5 = WH[(size_t)5 * G4 + row1];
    uint4 h0c6 = WH[(size_t)6 * G4 + row0], h1c6 = WH[(size_t)6 * G4 + row1];
    uint4 h0c7 = WH[(size_t)7 * G4 + row0], h1c7 = WH[(size_t)7 * G4 + row1];

    // Wih stream bases (L2-resident, off critical path)
    const uint4* WI0;
    if constexpr (LAYER == 0) WI0 = pwi + ((size_t)(kg * NJX)) * G4;
    else                      WI0 = pwi + ((size_t)(LOFF * 64 + kg * 8)) * G4;

    // ---- per-update-thread bias + cell state ----
    const int b0 = tid >> 5, uu = tid & 31;
    const bool upd = tid < SB * 32;
    float biasv[4] = {0.f, 0.f, 0.f, 0.f};
    float cst = 0.0f;
    if (upd) {
        #pragma unroll
        for (int Gx = 0; Gx < 4; Gx++) {
            int RR = Gx * H_ + U0 + uu;
            if constexpr (LAYER == 0)
                biasv[Gx] = biasA[(size_t)(sb0 + b0) * G4 + RR];   // mc (incl. biases)
            else
                biasv[Gx] = biasA[RR] + biasB[RR];
        }
    }
    const size_t wslot = (size_t)(sb0 + b0) * 512 + U0 + uu;   // pair this thread writes
    // residual/x_out address pieces for the upd thread
    const int usb = sb0 + b0, ubg = usb >> LAYER, uk = usb & (DIL - 1);

    // ---- prologue: prefetch token 0 ----
    float xsr[XRS];
    #pragma unroll
    for (int rr = 0; rr < XRS; rr++) {
        int idx = tid + rr * 512;
        if (idx < XTOT) {
            int b = idx >> KSH, off = idx & (KIN - 1);
            int sb = sb0 + b, bg = sb >> LAYER, k = sb & (DIL - 1);
            xsr[rr] = __hip_atomic_load(
                x_in + ((size_t)bg * S_ + k) * KIN + off,
                __ATOMIC_RELAXED, SCOPE_AGENT);
        }
    }
    // drain prologue prefetch, then publish h_{-1}=0 with tag=base (buf[1])
    asm volatile("s_waitcnt vmcnt(0)" ::: "memory");
    __syncthreads();
    if (upd)
        __hip_atomic_store(hp + HPH + wslot,
                           (unsigned long long)tagbase << 32,
                           __ATOMIC_RELAXED, SCOPE_AGENT);

    float accA[SB], accB[SB];
    for (int t = 0; t < T; t++) {
        // ---- staged regs -> LDS (packed f16) ----
        #pragma unroll
        for (int rr = 0; rr < XRS; rr++) {
            int idx = tid + rr * 512;
            if (idx < XTOT) lds_x[idx >> KSH][idx & (KIN - 1)] = f2h(xsr[rr]);
        }
        __syncthreads();   // (a)

        // ---- issue token(t+1) prefetch (drained before publish) ----
        if (t + 1 < T) {
            #pragma unroll
            for (int rr = 0; rr < XRS; rr++) {
                int idx = tid + rr * 512;
                if (idx < XTOT) {
                    int b = idx >> KSH, off = idx & (KIN - 1);
                    int sb = sb0 + b, bg = sb >> LAYER, k = sb & (DIL - 1);
                    xsr[rr] = __hip_atomic_load(
                        x_in + ((size_t)bg * S_ + (size_t)(t + 1) * DIL + k) * KIN + off,
                        __ATOMIC_RELAXED, SCOPE_AGENT);
                }
            }
        }

        // ---- early residual load (own slot; we are its only writer) ----
        float res = 0.f;
        if constexpr (LAYER > 0) {
            if (upd)
                res = __hip_atomic_load(
                    x_in + ((size_t)ubg * S_ + (size_t)t * DIL + uk) * H_ + U0 + uu,
                    __ATOMIC_RELAXED, SCOPE_AGENT);
        }

        // ---- issue first h-pair polls (detect overlaps x-matvec) ----
        const unsigned long long* hrd = hp + (size_t)((t + 1) & 1) * HPH;
        unsigned long long pv[SB];
        #pragma unroll
        for (int b = 0; b < SB; b++)
            pv[b] = __hip_atomic_load(hrd + (size_t)(sb0 + b) * 512 + tid,
                                      __ATOMIC_RELAXED, SCOPE_AGENT);

        // ---- x-part: stream Wih chunks, reuse across SB and 2 rows ----
        #pragma unroll
        for (int b = 0; b < SB; b++) { accA[b] = 0.f; accB[b] = 0.f; }
        #pragma unroll
        for (int j = 0; j < NJX; j++) {
            uint4 w0 = WI0[(size_t)j * G4 + row0];
            uint4 w1 = WI0[(size_t)j * G4 + row1];
            #pragma unroll
            for (int b = 0; b < SB; b++) {
                uint4 xv = *(const uint4*)&lds_x[b][kg * (KIN / 8) + j * 8];
                accA[b] = dot8f(w0, xv, accA[b]);
                accB[b] = dot8f(w1, xv, accB[b]);
            }
        }

        // ---- complete polls; h values -> LDS (packed f16) ----
        {
            const unsigned int want = tagbase + (unsigned int)t;
            #pragma unroll
            for (int b = 0; b < SB; b++) {
                while ((unsigned int)(pv[b] >> 32) != want)
                    pv[b] = __hip_atomic_load(hrd + (size_t)(sb0 + b) * 512 + tid,
                                              __ATOMIC_RELAXED, SCOPE_AGENT);
                lds_h[b][tid] = f2h(__uint_as_float((unsigned int)pv[b]));
            }
        }
        __syncthreads();   // (b)

        // ---- recurrent part: register-resident Whh, fdot2 ----
        HSTEP(0) HSTEP(1) HSTEP(2) HSTEP(3)
        HSTEP(4) HSTEP(5) HSTEP(6) HSTEP(7)

        // ---- partials; drain prefetch+res; barrier (c) ----
        #pragma unroll
        for (int b = 0; b < SB; b++) {
            lds_p[b][kg][rl0] = accA[b];
            lds_p[b][kg][rl1] = accB[b];
        }
        asm volatile("s_waitcnt vmcnt(0)" ::: "memory");
        __syncthreads();   // (c) partials visible AND all prefetch drained

        // ---- gates + publish (then x_out store, off the publish path) ----
        if (upd) {
            float gv[4];
            #pragma unroll
            for (int Gx = 0; Gx < 4; Gx++) {
                int rl = Gx * 32 + uu;
                float s = biasv[Gx];
                #pragma unroll
                for (int q = 0; q < 8; q++) s += lds_p[b0][q][rl];
                gv[Gx] = s;
            }
            float ci = sigm(gv[0]), cf = sigm(gv[1]);
            float cg = tanhfast(gv[2]), co = sigm(gv[3]);
            cst = cf * cst + ci * cg;
            float hv = co * tanhfast(cst);
            unsigned long long pk =
                ((unsigned long long)(tagbase + (unsigned int)t + 1) << 32) |
                (unsigned long long)__float_as_uint(hv);
            __hip_atomic_store(hp + (size_t)(t & 1) * HPH + wslot,
                               pk, __ATOMIC_RELAXED, SCOPE_AGENT);
            __hip_atomic_store(x_out + ((size_t)ubg * S_ + (size_t)t * DIL + uk) * H_ + U0 + uu,
                               hv + res, __ATOMIC_RELAXED, SCOPE_AGENT);
        }
    }
}

// ---------------------------------------------------------------------------
// out = x @ W_out.T + b_out   ([16384,512] x [512,128])
// ---------------------------------------------------------------------------
__global__ __launch_bounds__(256) void out_gemm(
    const float* __restrict__ x, const float* __restrict__ Wout,
    const float* __restrict__ bout, float* __restrict__ out)
{
    __shared__ __align__(16) float xs[8][H_];
    int tid = threadIdx.x;
    size_t tok0 = (size_t)blockIdx.x * 8;
    const float4* src = (const float4*)(x + tok0 * H_);
    for (int idx = tid; idx < 8 * H_ / 4; idx += 256)
        ((float4*)xs)[idx] = src[idx];
    __syncthreads();

    int col = tid & 127, th = tid >> 7;
    int tb = th * 4;
    float a0 = 0.f, a1 = 0.f, a2 = 0.f, a3 = 0.f;
    const float4* w = (const float4*)(Wout + (size_t)col * H_);
    #pragma unroll 4
    for (int j = 0; j < H_ / 4; j++) {
        float4 wv = w[j];
        float4 x0 = ((const float4*)xs[tb + 0])[j];
        float4 x1 = ((const float4*)xs[tb + 1])[j];
        float4 x2 = ((const float4*)xs[tb + 2])[j];
        float4 x3 = ((const float4*)xs[tb + 3])[j];
        a0 = fmaf(wv.x, x0.x, a0); a0 = fmaf(wv.y, x0.y, a0); a0 = fmaf(wv.z, x0.z, a0); a0 = fmaf(wv.w, x0.w, a0);
        a1 = fmaf(wv.x, x1.x, a1); a1 = fmaf(wv.y, x1.y, a1); a1 = fmaf(wv.z, x1.z, a1); a1 = fmaf(wv.w, x1.w, a1);
        a2 = fmaf(wv.x, x2.x, a2); a2 = fmaf(wv.y, x2.y, a2); a2 = fmaf(wv.z, x2.z, a2); a2 = fmaf(wv.w, x2.w, a2);
        a3 = fmaf(wv.x, x3.x, a3); a3 = fmaf(wv.y, x3.y, a3); a3 = fmaf(wv.z, x3.z, a3); a3 = fmaf(wv.w, x3.w, a3);
    }
    float bo = bout[col];
    out[(tok0 + tb + 0) * FR + col] = a0 + bo;
    out[(tok0 + tb + 1) * FR + col] = a1 + bo;
    out[(tok0 + tb + 2) * FR + col] = a2 + bo;
    out[(tok0 + tb + 3) * FR + col] = a3 + bo;
}

// ---------------------------------------------------------------------------
extern "C" void kernel_launch(void* const* d_in, const int* in_sizes, int n_in,
                              void* d_out, int out_size, void* d_ws, size_t ws_size,
                              hipStream_t stream)
{
    const float* inputs = (const float*)d_in[0];
    const float* moods  = (const float*)d_in[1];
    const float* W_mood = (const float*)d_in[2];
    const float* b_mood = (const float*)d_in[3];
    const float* W_ih0  = (const float*)d_in[4];
    const float* W_hh0  = (const float*)d_in[5];
    const float* b_ih0  = (const float*)d_in[6];
    const float* b_hh0  = (const float*)d_in[7];
    const float* W_ih_r = (const float*)d_in[8];
    const float* W_hh_r = (const float*)d_in[9];
    const float* b_ih_r = (const float*)d_in[10];
    const float* b_hh_r = (const float*)d_in[11];
    const float* W_out  = (const float*)d_in[12];
    const float* b_out  = (const float*)d_in[13];

    float* ws = (float*)d_ws;
    float* mc = ws;                                    // 32768 floats
    float* xA = ws + 32768;                            // 8388608 floats (in-place x)
    unsigned long long* hp = (unsigned long long*)(xA + 8388608);  // 2*HPH pairs = 1MB
    uint4* pwh  = (uint4*)(hp + 2 * HPH);              // 524288 uint4
    uint4* pwi0 = pwh + NCH_WHH;                       // 32768 uint4
    uint4* pwir = pwi0 + NCH_WI0;                      // 393216 uint4
    // total ~50 MB

    hipMemsetAsync(hp, 0, 2 * HPH * sizeof(unsigned long long), stream);
    mood_kernel<<<16, 256, 0, stream>>>(moods, W_mood, b_mood, W_ih0, b_ih0, b_hh0, mc);
    pack_kernel<<<(NCH_TOT + 255) / 256, 256, 0, stream>>>(
        W_hh0, W_hh_r, W_ih0, W_ih_r, pwh, pwi0, pwir);

    // tag bases strictly increasing across layers (memset clears stale tags
    // between graph replays).
    scan_kernel<0><<<256, 512, 0, stream>>>(inputs, xA, pwi0, pwh, mc, nullptr, hp, 1u);
    scan_kernel<1><<<256, 512, 0, stream>>>(xA, xA, pwir, pwh,
                                            b_ih_r, b_hh_r, hp, 1026u);
    scan_kernel<2><<<256, 512, 0, stream>>>(xA, xA, pwir, pwh,
                                            b_ih_r + G4, b_hh_r + G4, hp, 1539u);
    scan_kernel<3><<<256, 512, 0, stream>>>(xA, xA, pwir, pwh,
                                            b_ih_r + 2 * G4, b_hh_r + 2 * G4, hp, 1796u);

    out_gemm<<<2048, 256, 0, stream>>>(xA, W_out, b_out, (float*)d_out);
}